// Round 1
// baseline (311.425 us; speedup 1.0000x reference)
//
#include <hip/hip_runtime.h>

// Temporal shift: B=64, T=128, N=21, C=256, U=1.
// Partitions of C: [0,86) shift -1 (out[t]=x[t+1]); [86,171) shift 0;
// [171,256) shift +1 (out[t]=x[t-1]). Zero-fill out-of-range t.
// Layout (B,T,N,C) row-major: one (b,t) slice = N*C = 5376 floats = 1344 float4.
//
// Design (v2):
//  - One block per (b,t) slice -> t is block-uniform (SGPR), no div-by-21.
//  - 448 threads x 3 unrolled iters = 1344 float4 per slice; c4 = tid&63 is
//    iteration-invariant (448 = 7*64), so shift classification happens once.
//  - Straddle groups c4==21 (floats 84..87: s=-1|s=0) and c4==42 (floats
//    168..171: s=0|s=+1) are handled with TWO aligned float4 loads + a
//    component blend instead of 4 scalar loads + 4 scalar stores. Every lane
//    now issues exactly one full float4 store -> the wave store is one
//    contiguous 1024B request (previously fragmented into 3 segments + 8
//    scalar requests).
//  - Non-temporal stores: output is never re-read in-kernel.

typedef float v4f __attribute__((ext_vector_type(4)));

#define NT_T   128
#define NT_N   21
#define NT_C   256
#define ROW_V  (NT_N * NT_C / 4)   // 1344 float4 per (b,t) slice = t-stride
#define BLOCK  448                 // 7 waves; 448*3 = 1344
#define ITERS  3

__global__ __launch_bounds__(BLOCK) void temporal_shift_kernel(
    const v4f* __restrict__ xv, v4f* __restrict__ ov)
{
    const int bt   = blockIdx.x;                 // b*T + t  (grid = B*T = 8192)
    const int t    = bt & (NT_T - 1);            // block-uniform scalar
    const int base = bt * ROW_V + threadIdx.x;   // max < 11,010,048 -> int ok
    const int c4   = threadIdx.x & 63;           // invariant across iters

    const v4f zero = {0.f, 0.f, 0.f, 0.f};

    if (c4 == 21) {
        // floats 84,85 from t+1 (s=-1); floats 86,87 from t (s=0)
        #pragma unroll
        for (int k = 0; k < ITERS; ++k) {
            const int i = base + k * BLOCK;
            v4f va = (t < NT_T - 1) ? xv[i + ROW_V] : zero;
            v4f vb = xv[i];
            v4f r = {va.x, va.y, vb.z, vb.w};
            __builtin_nontemporal_store(r, &ov[i]);
        }
    } else if (c4 == 42) {
        // floats 168,169,170 from t (s=0); float 171 from t-1 (s=+1)
        #pragma unroll
        for (int k = 0; k < ITERS; ++k) {
            const int i = base + k * BLOCK;
            v4f vb = xv[i];
            v4f vc = (t > 0) ? xv[i - ROW_V] : zero;
            v4f r = {vb.x, vb.y, vb.z, vc.w};
            __builtin_nontemporal_store(r, &ov[i]);
        }
    } else {
        // Uniform-shift groups: c4 in [0,20] -> s=-1; [22,41] -> s=0; [43,63] -> s=+1
        const int  s     = (c4 <= 20) ? -1 : ((c4 <= 41) ? 0 : 1);
        const bool valid = ((unsigned)(t - s)) < (unsigned)NT_T; // only fails at t=0/127
        const int  off   = valid ? -s * ROW_V : 0;               // clamp to in-bounds
        #pragma unroll
        for (int k = 0; k < ITERS; ++k) {
            const int i = base + k * BLOCK;
            v4f v = xv[i + off];
            v4f r = valid ? v : zero;
            __builtin_nontemporal_store(r, &ov[i]);
        }
    }
}

extern "C" void kernel_launch(void* const* d_in, const int* in_sizes, int n_in,
                              void* d_out, int out_size, void* d_ws, size_t ws_size,
                              hipStream_t stream)
{
    const v4f* x = (const v4f*)d_in[0];
    v4f* out = (v4f*)d_out;
    // One block per (b,t) slice.
    const int grid = 64 * NT_T;   // B*T = 8192
    temporal_shift_kernel<<<grid, BLOCK, 0, stream>>>(x, out);
}

// Round 2
// 290.585 us; speedup vs baseline: 1.0717x; 1.0717x over previous
//
#include <hip/hip_runtime.h>

// Temporal shift: B=64, T=128, N=21, C=256, U=1.
// Partitions of C: [0,86) shift -1 (out[t]=x[t+1]); [86,171) shift 0;
// [171,256) shift +1 (out[t]=x[t-1]). Zero-fill out-of-range t.
// Layout (B,T,N,C) row-major: t-stride = N*C = 5376 floats = 1344 float4.
//
// v3 design — branch-free, one float4 per thread:
//  - v2 post-mortem: per-wave 3-way divergence (every wave holds a c4==21 and
//    a c4==42 lane) serialized three load->wait->store chains per wave and
//    fragmented stores; dispatch regressed to 115us at ~3 TB/s effective.
//  - Here EVERY lane takes one uniform path: two wave-wide float4 loads
//    (A at the shift of component 0, B at the shift of component 3) + a
//    per-component compile-time-pattern blend + one contiguous 1024B wave
//    store. For 62/64 lanes A and B have identical addresses -> B is an L1
//    hit, no extra HBM traffic. No exec-mask churn, no scalar memory ops,
//    single vmcnt wait point.
//  - 256-thread blocks (8 blocks/CU = 32 waves, max occupancy), regular
//    cached stores (v2's non-temporal stores reverted).

typedef float v4f __attribute__((ext_vector_type(4)));

#define NT_T 128
#define NT_N 21
#define NT_C 256
#define T_STRIDE_V (NT_N * NT_C / 4)   // 1344 float4 per t step

__global__ __launch_bounds__(256) void temporal_shift_kernel(
    const v4f* __restrict__ xv, v4f* __restrict__ ov, int total_vec)
{
    int i = blockIdx.x * blockDim.x + threadIdx.x;
    if (i >= total_vec) return;

    const int c4  = i & 63;          // C/4 = 64 float4-groups per (b,t,n) row
    const int row = i >> 6;          // (b,t,n) row index
    const int t   = (row / NT_N) & (NT_T - 1);   // compiler magic-muls /21

    // Per-component shifts derive from channel c = 4*c4 + k:
    //   s(c) = c<86 ? -1 : c<171 ? 0 : +1
    // Within one float4 group, components 0..1 always share s0; component 2
    // differs only at c4==21; component 3 differs at c4==21 and c4==42.
    const int c0 = c4 << 2;
    const int s0 = (c0 < 86) ? -1 : ((c0 < 171) ? 0 : 1);
    const int s3 = (c0 + 3 < 86) ? -1 : ((c0 + 3 < 171) ? 0 : 1);

    const bool vA = ((unsigned)(t - s0)) < (unsigned)NT_T;  // source slice valid?
    const bool vB = ((unsigned)(t - s3)) < (unsigned)NT_T;

    // Clamp invalid addresses in-bounds; result masked to zero below.
    v4f A = xv[i - (vA ? s0 : 0) * T_STRIDE_V];
    v4f B = xv[i - (vB ? s3 : 0) * T_STRIDE_V];

    const v4f zero = {0.f, 0.f, 0.f, 0.f};
    if (!vA) A = zero;
    if (!vB) B = zero;

    v4f r;
    r.x = A.x;
    r.y = A.y;
    r.z = (c4 == 21) ? B.z : A.z;   // only group 21 splits at component 2
    r.w = (s3 != s0) ? B.w : A.w;   // groups 21 and 42 split at component 3

    ov[i] = r;
}

extern "C" void kernel_launch(void* const* d_in, const int* in_sizes, int n_in,
                              void* d_out, int out_size, void* d_ws, size_t ws_size,
                              hipStream_t stream)
{
    const v4f* x = (const v4f*)d_in[0];
    v4f* out = (v4f*)d_out;
    int total_vec = out_size / 4;   // 11,010,048 float4
    int block = 256;
    int grid = (total_vec + block - 1) / block;
    temporal_shift_kernel<<<grid, block, 0, stream>>>(x, out, total_vec);
}